// Round 1
// baseline (3586.324 us; speedup 1.0000x reference)
//
#include <hip/hip_runtime.h>
#include <hip/hip_bf16.h>
#include <math.h>

// Problem constants (fixed by the reference)
#define B_ROWS 16384
#define D_DIM  4096
#define H_DIM  2048
#define E_DIM  64
#define TEMP   0.8f

// ---------------------------------------------------------------------------
// K1: h = relu(x @ W1^T + b1)   x[B,D], W1[H,D] both row-major (K-contig, NT)
// 128x128 block tile, BK=8, 256 threads, 8x8 micro-tile per thread.
// ---------------------------------------------------------------------------
#define G1_BM 128
#define G1_BN 128
#define G1_BK 8
#define G1_TM 8
#define G1_TN 8

__global__ __launch_bounds__(256) void gemm1_relu_kernel(
    const float* __restrict__ A, const float* __restrict__ W1,
    const float* __restrict__ b1, float* __restrict__ Hout) {
  __shared__ float As[G1_BK][G1_BM];
  __shared__ float Bs[G1_BK][G1_BN];
  const int t  = threadIdx.x;
  const int m0 = blockIdx.y * G1_BM;
  const int n0 = blockIdx.x * G1_BN;
  const int tx = t & 15;        // n direction (16)
  const int ty = t >> 4;        // m direction (16)
  const int lr = t >> 1;        // 0..127 load row
  const int lc = (t & 1) * 4;   // 0 or 4 load col

  const float* Ap = A  + (size_t)(m0 + lr) * D_DIM + lc;
  const float* Bp = W1 + (size_t)(n0 + lr) * D_DIM + lc;

  float acc[G1_TM][G1_TN] = {};

  for (int k0 = 0; k0 < D_DIM; k0 += G1_BK) {
    float4 av = *(const float4*)(Ap + k0);
    float4 bv = *(const float4*)(Bp + k0);
    As[lc + 0][lr] = av.x; As[lc + 1][lr] = av.y;
    As[lc + 2][lr] = av.z; As[lc + 3][lr] = av.w;
    Bs[lc + 0][lr] = bv.x; Bs[lc + 1][lr] = bv.y;
    Bs[lc + 2][lr] = bv.z; Bs[lc + 3][lr] = bv.w;
    __syncthreads();
#pragma unroll
    for (int kk = 0; kk < G1_BK; ++kk) {
      float ra[G1_TM], rb[G1_TN];
#pragma unroll
      for (int i = 0; i < G1_TM; ++i) ra[i] = As[kk][ty * G1_TM + i];
#pragma unroll
      for (int j = 0; j < G1_TN; ++j) rb[j] = Bs[kk][tx * G1_TN + j];
#pragma unroll
      for (int i = 0; i < G1_TM; ++i)
#pragma unroll
        for (int j = 0; j < G1_TN; ++j) acc[i][j] += ra[i] * rb[j];
    }
    __syncthreads();
  }

  // Epilogue: bias + relu, vectorized store
  const int nb = n0 + tx * G1_TN;
  const float4 bb0 = *(const float4*)(b1 + nb);
  const float4 bb1 = *(const float4*)(b1 + nb + 4);
#pragma unroll
  for (int i = 0; i < G1_TM; ++i) {
    const int m = m0 + ty * G1_TM + i;
    float4 v0, v1;
    v0.x = fmaxf(acc[i][0] + bb0.x, 0.f);
    v0.y = fmaxf(acc[i][1] + bb0.y, 0.f);
    v0.z = fmaxf(acc[i][2] + bb0.z, 0.f);
    v0.w = fmaxf(acc[i][3] + bb0.w, 0.f);
    v1.x = fmaxf(acc[i][4] + bb1.x, 0.f);
    v1.y = fmaxf(acc[i][5] + bb1.y, 0.f);
    v1.z = fmaxf(acc[i][6] + bb1.z, 0.f);
    v1.w = fmaxf(acc[i][7] + bb1.w, 0.f);
    *(float4*)(&Hout[(size_t)m * H_DIM + nb])     = v0;
    *(float4*)(&Hout[(size_t)m * H_DIM + nb + 4]) = v1;
  }
}

// ---------------------------------------------------------------------------
// K2: logits = h @ W2^T + b2    h[B,H], W2[E,H] row-major. N = E_DIM = 64.
// 64x64 block tile, BK=16, 256 threads, 2x8 micro-tile.
// ---------------------------------------------------------------------------
#define G2_BM 64
#define G2_BN 64
#define G2_BK 16
#define G2_TM 2
#define G2_TN 8

__global__ __launch_bounds__(256) void gemm2_kernel(
    const float* __restrict__ Hin, const float* __restrict__ W2,
    const float* __restrict__ b2, float* __restrict__ logits) {
  __shared__ float As[G2_BK][G2_BM];
  __shared__ float Bs[G2_BK][G2_BN];
  const int t  = threadIdx.x;
  const int m0 = blockIdx.x * G2_BM;
  const int tx = t & 7;         // n direction (8) -> n = tx*8
  const int ty = t >> 3;        // m direction (32) -> m = ty*2
  const int lr = t >> 2;        // 0..63
  const int lc = (t & 3) * 4;   // 0,4,8,12

  const float* Ap = Hin + (size_t)(m0 + lr) * H_DIM + lc;
  const float* Bp = W2  + (size_t)lr * H_DIM + lc;

  float acc[G2_TM][G2_TN] = {};

  for (int k0 = 0; k0 < H_DIM; k0 += G2_BK) {
    float4 av = *(const float4*)(Ap + k0);
    float4 bv = *(const float4*)(Bp + k0);
    As[lc + 0][lr] = av.x; As[lc + 1][lr] = av.y;
    As[lc + 2][lr] = av.z; As[lc + 3][lr] = av.w;
    Bs[lc + 0][lr] = bv.x; Bs[lc + 1][lr] = bv.y;
    Bs[lc + 2][lr] = bv.z; Bs[lc + 3][lr] = bv.w;
    __syncthreads();
#pragma unroll
    for (int kk = 0; kk < G2_BK; ++kk) {
      float ra[G2_TM], rb[G2_TN];
#pragma unroll
      for (int i = 0; i < G2_TM; ++i) ra[i] = As[kk][ty * G2_TM + i];
#pragma unroll
      for (int j = 0; j < G2_TN; ++j) rb[j] = Bs[kk][tx * G2_TN + j];
#pragma unroll
      for (int i = 0; i < G2_TM; ++i)
#pragma unroll
        for (int j = 0; j < G2_TN; ++j) acc[i][j] += ra[i] * rb[j];
    }
    __syncthreads();
  }

  const int nb = tx * G2_TN;
  const float4 bb0 = *(const float4*)(b2 + nb);
  const float4 bb1 = *(const float4*)(b2 + nb + 4);
#pragma unroll
  for (int i = 0; i < G2_TM; ++i) {
    const int m = m0 + ty * G2_TM + i;
    float4 v0, v1;
    v0.x = acc[i][0] + bb0.x; v0.y = acc[i][1] + bb0.y;
    v0.z = acc[i][2] + bb0.z; v0.w = acc[i][3] + bb0.w;
    v1.x = acc[i][4] + bb1.x; v1.y = acc[i][5] + bb1.y;
    v1.z = acc[i][6] + bb1.z; v1.w = acc[i][7] + bb1.w;
    *(float4*)(&logits[(size_t)m * E_DIM + nb])     = v0;
    *(float4*)(&logits[(size_t)m * E_DIM + nb + 4]) = v1;
  }
}

// ---------------------------------------------------------------------------
// K3: per-row top-2 (stable ties -> lowest index, matches lax.top_k),
// temperature-softmax renorm weights, entropy of UN-scaled softmax.
// One thread per row.
// ---------------------------------------------------------------------------
__global__ __launch_bounds__(256) void router_kernel(
    const float* __restrict__ logits, float* __restrict__ out,
    float* __restrict__ accum) {
  const int row = blockIdx.x * 256 + threadIdx.x;

  float l[E_DIM];
  const float4* lp = (const float4*)(logits + (size_t)row * E_DIM);
#pragma unroll
  for (int q = 0; q < E_DIM / 4; ++q) {
    float4 v = lp[q];
    l[q * 4 + 0] = v.x; l[q * 4 + 1] = v.y;
    l[q * 4 + 2] = v.z; l[q * 4 + 3] = v.w;
  }

  // stable top-2: ties keep the lowest index (strict > comparisons)
  float l0 = l[0]; int i0 = 0;
  float l1 = -INFINITY; int i1 = -1;
#pragma unroll
  for (int e = 1; e < E_DIM; ++e) {
    float v = l[e];
    if (v > l0)      { l1 = l0; i1 = i0; l0 = v; i0 = e; }
    else if (v > l1) { l1 = v; i1 = e; }
  }

  // renormalized top-2 weights of softmax(l/T): w0 = 1/(1+e^{(l1-l0)/T})
  const float eT = expf((l1 - l0) / TEMP);
  const float w0 = 1.f / (1.f + eT);
  const float w1 = eT / (1.f + eT);

  // entropy of softmax(l) (T = 1), stable via max = l0
  float Z = 0.f;
#pragma unroll
  for (int e = 0; e < E_DIM; ++e) Z += expf(l[e] - l0);
  const float invZ = 1.f / Z;
  float ent = 0.f;
#pragma unroll
  for (int e = 0; e < E_DIM; ++e) {
    float p = expf(l[e] - l0) * invZ;
    ent -= p * logf(p + 1e-10f);
  }

  // outputs: weights [B,2], then indices [B,2] (as float), then scalar
  out[(size_t)row * 2 + 0] = w0;
  out[(size_t)row * 2 + 1] = w1;
  out[(size_t)B_ROWS * 2 + (size_t)row * 2 + 0] = (float)i0;
  out[(size_t)B_ROWS * 2 + (size_t)row * 2 + 1] = (float)i1;

  // block-reduce entropy, one atomic per block
  __shared__ float se[256];
  se[threadIdx.x] = ent;
  __syncthreads();
  for (int s = 128; s > 0; s >>= 1) {
    if (threadIdx.x < s) se[threadIdx.x] += se[threadIdx.x + s];
    __syncthreads();
  }
  if (threadIdx.x == 0) atomicAdd(accum, se[0]);
}

__global__ void zero_kernel(float* p) { p[0] = 0.f; }

__global__ void finalize_kernel(const float* __restrict__ accum,
                                float* __restrict__ out) {
  out[(size_t)B_ROWS * 4] = accum[0] / ((float)B_ROWS * logf((float)E_DIM));
}

// ---------------------------------------------------------------------------
extern "C" void kernel_launch(void* const* d_in, const int* in_sizes, int n_in,
                              void* d_out, int out_size, void* d_ws,
                              size_t ws_size, hipStream_t stream) {
  const float* x  = (const float*)d_in[0];
  const float* W1 = (const float*)d_in[1];
  const float* b1 = (const float*)d_in[2];
  const float* W2 = (const float*)d_in[3];
  const float* b2 = (const float*)d_in[4];
  float* out = (float*)d_out;

  float* ws     = (float*)d_ws;
  float* h      = ws;                                  // B*H floats (128 MiB)
  float* logits = ws + (size_t)B_ROWS * H_DIM;         // B*E floats (4 MiB)
  float* accum  = logits + (size_t)B_ROWS * E_DIM;     // 1 float

  zero_kernel<<<1, 1, 0, stream>>>(accum);

  dim3 g1(H_DIM / G1_BN, B_ROWS / G1_BM);              // (16, 128)
  gemm1_relu_kernel<<<g1, 256, 0, stream>>>(x, W1, b1, h);

  gemm2_kernel<<<B_ROWS / G2_BM, 256, 0, stream>>>(h, W2, b2, logits);

  router_kernel<<<B_ROWS / 256, 256, 0, stream>>>(logits, out, accum);

  finalize_kernel<<<1, 1, 0, stream>>>(accum, out);
}

// Round 2
// 1337.727 us; speedup vs baseline: 2.6809x; 2.6809x over previous
//
#include <hip/hip_runtime.h>
#include <hip/hip_bf16.h>
#include <math.h>

// Problem constants (fixed by the reference)
#define B_ROWS 16384
#define D_DIM  4096
#define H_DIM  2048
#define E_DIM  64
#define TEMP   0.8f

typedef __bf16 bf16x8 __attribute__((ext_vector_type(8)));
typedef float  f32x4  __attribute__((ext_vector_type(4)));
typedef unsigned short ushort8 __attribute__((ext_vector_type(8)));

__device__ __forceinline__ unsigned short bf_rne(float f) {
  unsigned u = __float_as_uint(f);
  u += 0x7FFF + ((u >> 16) & 1);
  return (unsigned short)(u >> 16);
}

__device__ __forceinline__ void async_copy16(const void* g, void* l) {
  __builtin_amdgcn_global_load_lds(
      (const __attribute__((address_space(1))) void*)g,
      (__attribute__((address_space(3))) void*)l, 16, 0, 0);
}

// ---------------------------------------------------------------------------
// split: fp32 -> (hi bf16, lo bf16), RNE both. 8 elements / thread.
// ---------------------------------------------------------------------------
__global__ __launch_bounds__(256) void split_kernel(
    const float* __restrict__ in, unsigned short* __restrict__ hi,
    unsigned short* __restrict__ lo) {
  const size_t i = ((size_t)blockIdx.x * 256 + threadIdx.x) * 8;
  float4 v0 = *(const float4*)(in + i);
  float4 v1 = *(const float4*)(in + i + 4);
  float f[8] = {v0.x, v0.y, v0.z, v0.w, v1.x, v1.y, v1.z, v1.w};
  ushort8 hv, lv;
#pragma unroll
  for (int j = 0; j < 8; ++j) {
    unsigned short h = bf_rne(f[j]);
    float fh = __uint_as_float(((unsigned)h) << 16);
    hv[j] = h;
    lv[j] = bf_rne(f[j] - fh);
  }
  *(ushort8*)(hi + i) = hv;
  *(ushort8*)(lo + i) = lv;
}

// ---------------------------------------------------------------------------
// K1: h = relu(x @ W1^T + b1) via bf16x3 MFMA emulation of fp32.
// x[M,K] fp32 (split in-kernel), W1 pre-split hi/lo bf16 [N,K].
// BM=BN=128, BK=32, 256 threads = 4 waves in 2x2, each wave 64x64 via
// 4x4 frags of mfma_f32_16x16x32_bf16, 3 passes (hh, lh, hl).
// ---------------------------------------------------------------------------
#define BM 128
#define BN 128
#define BKK 32

__global__ __launch_bounds__(256) void gemm1_mfma_kernel(
    const float* __restrict__ x,
    const unsigned short* __restrict__ w1h,
    const unsigned short* __restrict__ w1l,
    const float* __restrict__ b1, float* __restrict__ Hout) {
  __shared__ unsigned short Ah[BM * BKK];  // 8 KB each
  __shared__ unsigned short Al[BM * BKK];
  __shared__ unsigned short Bh[BN * BKK];
  __shared__ unsigned short Bl[BN * BKK];

  const int t    = threadIdx.x;
  const int lane = t & 63;
  const int w    = t >> 6;          // wave 0..3
  const int wm   = w >> 1;          // wave m (2)
  const int wn   = w & 1;           // wave n (2)
  const int m0   = blockIdx.y * BM;
  const int n0   = blockIdx.x * BN;

  // --- B staging via global_load_lds: 2 insts per plane per wave ---
  // inst i covers bytes [(w*2+i)*1024, +1024) of the 8 KB plane tile.
  const int e0 = (w * 2 + 0) * 512 + lane * 8;   // element offset, inst 0
  const int e1 = (w * 2 + 1) * 512 + lane * 8;   // element offset, inst 1
  const int r0 = e0 >> 5, c0 = e0 & 31;
  const int r1 = e1 >> 5, c1 = e1 & 31;
  const unsigned short* bh_g0 = w1h + (size_t)(n0 + r0) * D_DIM + c0;
  const unsigned short* bh_g1 = w1h + (size_t)(n0 + r1) * D_DIM + c1;
  const unsigned short* bl_g0 = w1l + (size_t)(n0 + r0) * D_DIM + c0;
  const unsigned short* bl_g1 = w1l + (size_t)(n0 + r1) * D_DIM + c1;
  unsigned short* bh_l0 = &Bh[e0];
  unsigned short* bh_l1 = &Bh[e1];
  unsigned short* bl_l0 = &Bl[e0];
  unsigned short* bl_l1 = &Bl[e1];

  // --- A staging (fp32 -> hi/lo bf16 in-kernel): 16 floats / thread ---
  const int ar = t >> 1;            // row 0..127
  const int ac = (t & 1) * 16;      // col 0 or 16
  const float* xp = x + (size_t)(m0 + ar) * D_DIM + ac;
  unsigned short* ah_w = &Ah[ar * BKK + ac];
  unsigned short* al_w = &Al[ar * BKK + ac];

  // --- fragment LDS read addresses (k-invariant, single-buffered) ---
  const int koff = (lane >> 4) * 8;
  const unsigned short* a_rd[4];
  const unsigned short* b_rd[4];
#pragma unroll
  for (int f = 0; f < 4; ++f) {
    a_rd[f] = &Ah[(wm * 64 + f * 16 + (lane & 15)) * BKK + koff];
    b_rd[f] = &Bh[(wn * 64 + f * 16 + (lane & 15)) * BKK + koff];
  }
  const int lo_off_a = (int)(Al - Ah);  // element offset between planes
  const int lo_off_b = (int)(Bl - Bh);

  f32x4 acc[4][4];
#pragma unroll
  for (int i = 0; i < 4; ++i)
#pragma unroll
    for (int j = 0; j < 4; ++j) acc[i][j] = (f32x4)0.f;

  for (int k0 = 0; k0 < D_DIM; k0 += BKK) {
    // async B staging (hi + lo planes)
    async_copy16(bh_g0 + k0, bh_l0);
    async_copy16(bh_g1 + k0, bh_l1);
    async_copy16(bl_g0 + k0, bl_l0);
    async_copy16(bl_g1 + k0, bl_l1);

    // A staging: load 16 fp32, split, write hi/lo to LDS
    float4 v[4];
#pragma unroll
    for (int j = 0; j < 4; ++j) v[j] = *(const float4*)(xp + k0 + j * 4);
    float f[16] = {v[0].x, v[0].y, v[0].z, v[0].w, v[1].x, v[1].y, v[1].z, v[1].w,
                   v[2].x, v[2].y, v[2].z, v[2].w, v[3].x, v[3].y, v[3].z, v[3].w};
    ushort8 hv0, hv1, lv0, lv1;
#pragma unroll
    for (int j = 0; j < 8; ++j) {
      unsigned short h = bf_rne(f[j]);
      float fh = __uint_as_float(((unsigned)h) << 16);
      hv0[j] = h;
      lv0[j] = bf_rne(f[j] - fh);
    }
#pragma unroll
    for (int j = 0; j < 8; ++j) {
      unsigned short h = bf_rne(f[8 + j]);
      float fh = __uint_as_float(((unsigned)h) << 16);
      hv1[j] = h;
      lv1[j] = bf_rne(f[8 + j] - fh);
    }
    *(ushort8*)(ah_w)     = hv0;
    *(ushort8*)(ah_w + 8) = hv1;
    *(ushort8*)(al_w)     = lv0;
    *(ushort8*)(al_w + 8) = lv1;

    __syncthreads();

    bf16x8 fa_h[4], fa_l[4], fb_h[4], fb_l[4];
#pragma unroll
    for (int ff = 0; ff < 4; ++ff) {
      fa_h[ff] = *(const bf16x8*)(a_rd[ff]);
      fa_l[ff] = *(const bf16x8*)(a_rd[ff] + lo_off_a);
      fb_h[ff] = *(const bf16x8*)(b_rd[ff]);
      fb_l[ff] = *(const bf16x8*)(b_rd[ff] + lo_off_b);
    }
#pragma unroll
    for (int i = 0; i < 4; ++i)
#pragma unroll
      for (int j = 0; j < 4; ++j) {
        acc[i][j] = __builtin_amdgcn_mfma_f32_16x16x32_bf16(fa_h[i], fb_h[j], acc[i][j], 0, 0, 0);
        acc[i][j] = __builtin_amdgcn_mfma_f32_16x16x32_bf16(fa_l[i], fb_h[j], acc[i][j], 0, 0, 0);
        acc[i][j] = __builtin_amdgcn_mfma_f32_16x16x32_bf16(fa_h[i], fb_l[j], acc[i][j], 0, 0, 0);
      }
    __syncthreads();
  }

  // Epilogue: bias + relu, C layout col=lane&15, row=(lane>>4)*4+reg
#pragma unroll
  for (int fn = 0; fn < 4; ++fn) {
    const int n = n0 + wn * 64 + fn * 16 + (lane & 15);
    const float bias = b1[n];
#pragma unroll
    for (int fm = 0; fm < 4; ++fm) {
      const int mbase = m0 + wm * 64 + fm * 16 + (lane >> 4) * 4;
#pragma unroll
      for (int r = 0; r < 4; ++r) {
        float vv = acc[fm][fn][r] + bias;
        Hout[(size_t)(mbase + r) * H_DIM + n] = fmaxf(vv, 0.f);
      }
    }
  }
}

// ---------------------------------------------------------------------------
// K2: logits = h @ W2^T + b2   (fp32 vector, memory-bound)
// ---------------------------------------------------------------------------
#define G2_BM 64
#define G2_BN 64
#define G2_BK 16
#define G2_TM 2
#define G2_TN 8

__global__ __launch_bounds__(256) void gemm2_kernel(
    const float* __restrict__ Hin, const float* __restrict__ W2,
    const float* __restrict__ b2, float* __restrict__ logits) {
  __shared__ float As[G2_BK][G2_BM];
  __shared__ float Bs[G2_BK][G2_BN];
  const int t  = threadIdx.x;
  const int m0 = blockIdx.x * G2_BM;
  const int tx = t & 7;
  const int ty = t >> 3;
  const int lr = t >> 2;
  const int lc = (t & 3) * 4;

  const float* Ap = Hin + (size_t)(m0 + lr) * H_DIM + lc;
  const float* Bp = W2  + (size_t)lr * H_DIM + lc;

  float acc[G2_TM][G2_TN] = {};

  for (int k0 = 0; k0 < H_DIM; k0 += G2_BK) {
    float4 av = *(const float4*)(Ap + k0);
    float4 bv = *(const float4*)(Bp + k0);
    As[lc + 0][lr] = av.x; As[lc + 1][lr] = av.y;
    As[lc + 2][lr] = av.z; As[lc + 3][lr] = av.w;
    Bs[lc + 0][lr] = bv.x; Bs[lc + 1][lr] = bv.y;
    Bs[lc + 2][lr] = bv.z; Bs[lc + 3][lr] = bv.w;
    __syncthreads();
#pragma unroll
    for (int kk = 0; kk < G2_BK; ++kk) {
      float ra[G2_TM], rb[G2_TN];
#pragma unroll
      for (int i = 0; i < G2_TM; ++i) ra[i] = As[kk][ty * G2_TM + i];
#pragma unroll
      for (int j = 0; j < G2_TN; ++j) rb[j] = Bs[kk][tx * G2_TN + j];
#pragma unroll
      for (int i = 0; i < G2_TM; ++i)
#pragma unroll
        for (int j = 0; j < G2_TN; ++j) acc[i][j] += ra[i] * rb[j];
    }
    __syncthreads();
  }

  const int nb = tx * G2_TN;
  const float4 bb0 = *(const float4*)(b2 + nb);
  const float4 bb1 = *(const float4*)(b2 + nb + 4);
#pragma unroll
  for (int i = 0; i < G2_TM; ++i) {
    const int m = m0 + ty * G2_TM + i;
    float4 v0, v1;
    v0.x = acc[i][0] + bb0.x; v0.y = acc[i][1] + bb0.y;
    v0.z = acc[i][2] + bb0.z; v0.w = acc[i][3] + bb0.w;
    v1.x = acc[i][4] + bb1.x; v1.y = acc[i][5] + bb1.y;
    v1.z = acc[i][6] + bb1.z; v1.w = acc[i][7] + bb1.w;
    *(float4*)(&logits[(size_t)m * E_DIM + nb])     = v0;
    *(float4*)(&logits[(size_t)m * E_DIM + nb + 4]) = v1;
  }
}

// ---------------------------------------------------------------------------
// K3: per-row top-2 + softmax weights + entropy (unchanged, verified)
// ---------------------------------------------------------------------------
__global__ __launch_bounds__(256) void router_kernel(
    const float* __restrict__ logits, float* __restrict__ out,
    float* __restrict__ accum) {
  const int row = blockIdx.x * 256 + threadIdx.x;

  float l[E_DIM];
  const float4* lp = (const float4*)(logits + (size_t)row * E_DIM);
#pragma unroll
  for (int q = 0; q < E_DIM / 4; ++q) {
    float4 v = lp[q];
    l[q * 4 + 0] = v.x; l[q * 4 + 1] = v.y;
    l[q * 4 + 2] = v.z; l[q * 4 + 3] = v.w;
  }

  float l0 = l[0]; int i0 = 0;
  float l1 = -INFINITY; int i1 = -1;
#pragma unroll
  for (int e = 1; e < E_DIM; ++e) {
    float v = l[e];
    if (v > l0)      { l1 = l0; i1 = i0; l0 = v; i0 = e; }
    else if (v > l1) { l1 = v; i1 = e; }
  }

  const float eT = expf((l1 - l0) / TEMP);
  const float w0 = 1.f / (1.f + eT);
  const float w1 = eT / (1.f + eT);

  float Z = 0.f;
#pragma unroll
  for (int e = 0; e < E_DIM; ++e) Z += expf(l[e] - l0);
  const float invZ = 1.f / Z;
  float ent = 0.f;
#pragma unroll
  for (int e = 0; e < E_DIM; ++e) {
    float p = expf(l[e] - l0) * invZ;
    ent -= p * logf(p + 1e-10f);
  }

  out[(size_t)row * 2 + 0] = w0;
  out[(size_t)row * 2 + 1] = w1;
  out[(size_t)B_ROWS * 2 + (size_t)row * 2 + 0] = (float)i0;
  out[(size_t)B_ROWS * 2 + (size_t)row * 2 + 1] = (float)i1;

  __shared__ float se[256];
  se[threadIdx.x] = ent;
  __syncthreads();
  for (int s = 128; s > 0; s >>= 1) {
    if (threadIdx.x < s) se[threadIdx.x] += se[threadIdx.x + s];
    __syncthreads();
  }
  if (threadIdx.x == 0) atomicAdd(accum, se[0]);
}

__global__ void zero_kernel(float* p) { p[0] = 0.f; }

__global__ void finalize_kernel(const float* __restrict__ accum,
                                float* __restrict__ out) {
  out[(size_t)B_ROWS * 4] = accum[0] / ((float)B_ROWS * logf((float)E_DIM));
}

// ---------------------------------------------------------------------------
extern "C" void kernel_launch(void* const* d_in, const int* in_sizes, int n_in,
                              void* d_out, int out_size, void* d_ws,
                              size_t ws_size, hipStream_t stream) {
  const float* x  = (const float*)d_in[0];
  const float* W1 = (const float*)d_in[1];
  const float* b1 = (const float*)d_in[2];
  const float* W2 = (const float*)d_in[3];
  const float* b2 = (const float*)d_in[4];
  float* out = (float*)d_out;

  // ws layout (bytes):
  //   w1h  : N*K bf16   = 16.8 MB
  //   w1l  : N*K bf16   = 16.8 MB
  //   h    : M*N fp32   = 134.2 MB
  //   logits : M*E fp32 = 4.2 MB
  //   accum  : 1 float
  unsigned short* w1h = (unsigned short*)d_ws;
  unsigned short* w1l = w1h + (size_t)H_DIM * D_DIM;
  float* h      = (float*)(w1l + (size_t)H_DIM * D_DIM);
  float* logits = h + (size_t)B_ROWS * H_DIM;
  float* accum  = logits + (size_t)B_ROWS * E_DIM;

  zero_kernel<<<1, 1, 0, stream>>>(accum);

  // split W1 -> hi/lo bf16 planes (8 elems/thread)
  const int w1_elems = H_DIM * D_DIM;
  split_kernel<<<w1_elems / (256 * 8), 256, 0, stream>>>(W1, w1h, w1l);

  dim3 g1(H_DIM / BN, B_ROWS / BM);  // (16, 128)
  gemm1_mfma_kernel<<<g1, 256, 0, stream>>>(x, w1h, w1l, b1, h);

  gemm2_kernel<<<B_ROWS / G2_BM, 256, 0, stream>>>(h, W2, b2, logits);

  router_kernel<<<B_ROWS / 256, 256, 0, stream>>>(logits, out, accum);

  finalize_kernel<<<1, 1, 0, stream>>>(accum, out);
}

// Round 3
// 1278.359 us; speedup vs baseline: 2.8054x; 1.0464x over previous
//
#include <hip/hip_runtime.h>
#include <hip/hip_bf16.h>
#include <math.h>

// Problem constants (fixed by the reference)
#define B_ROWS 16384
#define D_DIM  4096
#define H_DIM  2048
#define E_DIM  64
#define TEMP   0.8f

typedef __bf16 bf16x8 __attribute__((ext_vector_type(8)));
typedef float  f32x4  __attribute__((ext_vector_type(4)));
typedef unsigned short ushort8 __attribute__((ext_vector_type(8)));

__device__ __forceinline__ unsigned short bf_rne(float f) {
  unsigned u = __float_as_uint(f);
  u += 0x7FFF + ((u >> 16) & 1);
  return (unsigned short)(u >> 16);
}

__device__ __forceinline__ void async_copy16(const void* g, void* l) {
  __builtin_amdgcn_global_load_lds(
      (const __attribute__((address_space(1))) void*)g,
      (__attribute__((address_space(3))) void*)l, 16, 0, 0);
}

// ---------------------------------------------------------------------------
// split: fp32 -> (hi bf16, lo bf16), RNE both. 8 elements / thread.
// Used for W1 (16.8M elems) and W2 (131K elems).
// ---------------------------------------------------------------------------
__global__ __launch_bounds__(256) void split_kernel(
    const float* __restrict__ in, unsigned short* __restrict__ hi,
    unsigned short* __restrict__ lo) {
  const size_t i = ((size_t)blockIdx.x * 256 + threadIdx.x) * 8;
  float4 v0 = *(const float4*)(in + i);
  float4 v1 = *(const float4*)(in + i + 4);
  float f[8] = {v0.x, v0.y, v0.z, v0.w, v1.x, v1.y, v1.z, v1.w};
  ushort8 hv, lv;
#pragma unroll
  for (int j = 0; j < 8; ++j) {
    unsigned short h = bf_rne(f[j]);
    float fh = __uint_as_float(((unsigned)h) << 16);
    hv[j] = h;
    lv[j] = bf_rne(f[j] - fh);
  }
  *(ushort8*)(hi + i) = hv;
  *(ushort8*)(lo + i) = lv;
}

// ---------------------------------------------------------------------------
// K1: h = relu(x @ W1^T + b1) via bf16x3 MFMA emulation of fp32.
// UNCHANGED from R2 (990 us, 832 TF effective — at the m97-structure plateau).
// ---------------------------------------------------------------------------
#define BM 128
#define BN 128
#define BKK 32

__global__ __launch_bounds__(256) void gemm1_mfma_kernel(
    const float* __restrict__ x,
    const unsigned short* __restrict__ w1h,
    const unsigned short* __restrict__ w1l,
    const float* __restrict__ b1, float* __restrict__ Hout) {
  __shared__ unsigned short Ah[BM * BKK];  // 8 KB each
  __shared__ unsigned short Al[BM * BKK];
  __shared__ unsigned short Bh[BN * BKK];
  __shared__ unsigned short Bl[BN * BKK];

  const int t    = threadIdx.x;
  const int lane = t & 63;
  const int w    = t >> 6;          // wave 0..3
  const int wm   = w >> 1;          // wave m (2)
  const int wn   = w & 1;           // wave n (2)
  const int m0   = blockIdx.y * BM;
  const int n0   = blockIdx.x * BN;

  const int e0 = (w * 2 + 0) * 512 + lane * 8;
  const int e1 = (w * 2 + 1) * 512 + lane * 8;
  const int r0 = e0 >> 5, c0 = e0 & 31;
  const int r1 = e1 >> 5, c1 = e1 & 31;
  const unsigned short* bh_g0 = w1h + (size_t)(n0 + r0) * D_DIM + c0;
  const unsigned short* bh_g1 = w1h + (size_t)(n0 + r1) * D_DIM + c1;
  const unsigned short* bl_g0 = w1l + (size_t)(n0 + r0) * D_DIM + c0;
  const unsigned short* bl_g1 = w1l + (size_t)(n0 + r1) * D_DIM + c1;
  unsigned short* bh_l0 = &Bh[e0];
  unsigned short* bh_l1 = &Bh[e1];
  unsigned short* bl_l0 = &Bl[e0];
  unsigned short* bl_l1 = &Bl[e1];

  const int ar = t >> 1;
  const int ac = (t & 1) * 16;
  const float* xp = x + (size_t)(m0 + ar) * D_DIM + ac;
  unsigned short* ah_w = &Ah[ar * BKK + ac];
  unsigned short* al_w = &Al[ar * BKK + ac];

  const int koff = (lane >> 4) * 8;
  const unsigned short* a_rd[4];
  const unsigned short* b_rd[4];
#pragma unroll
  for (int f = 0; f < 4; ++f) {
    a_rd[f] = &Ah[(wm * 64 + f * 16 + (lane & 15)) * BKK + koff];
    b_rd[f] = &Bh[(wn * 64 + f * 16 + (lane & 15)) * BKK + koff];
  }
  const int lo_off_a = (int)(Al - Ah);
  const int lo_off_b = (int)(Bl - Bh);

  f32x4 acc[4][4];
#pragma unroll
  for (int i = 0; i < 4; ++i)
#pragma unroll
    for (int j = 0; j < 4; ++j) acc[i][j] = (f32x4)0.f;

  for (int k0 = 0; k0 < D_DIM; k0 += BKK) {
    async_copy16(bh_g0 + k0, bh_l0);
    async_copy16(bh_g1 + k0, bh_l1);
    async_copy16(bl_g0 + k0, bl_l0);
    async_copy16(bl_g1 + k0, bl_l1);

    float4 v[4];
#pragma unroll
    for (int j = 0; j < 4; ++j) v[j] = *(const float4*)(xp + k0 + j * 4);
    float f[16] = {v[0].x, v[0].y, v[0].z, v[0].w, v[1].x, v[1].y, v[1].z, v[1].w,
                   v[2].x, v[2].y, v[2].z, v[2].w, v[3].x, v[3].y, v[3].z, v[3].w};
    ushort8 hv0, hv1, lv0, lv1;
#pragma unroll
    for (int j = 0; j < 8; ++j) {
      unsigned short h = bf_rne(f[j]);
      float fh = __uint_as_float(((unsigned)h) << 16);
      hv0[j] = h;
      lv0[j] = bf_rne(f[j] - fh);
    }
#pragma unroll
    for (int j = 0; j < 8; ++j) {
      unsigned short h = bf_rne(f[8 + j]);
      float fh = __uint_as_float(((unsigned)h) << 16);
      hv1[j] = h;
      lv1[j] = bf_rne(f[8 + j] - fh);
    }
    *(ushort8*)(ah_w)     = hv0;
    *(ushort8*)(ah_w + 8) = hv1;
    *(ushort8*)(al_w)     = lv0;
    *(ushort8*)(al_w + 8) = lv1;

    __syncthreads();

    bf16x8 fa_h[4], fa_l[4], fb_h[4], fb_l[4];
#pragma unroll
    for (int ff = 0; ff < 4; ++ff) {
      fa_h[ff] = *(const bf16x8*)(a_rd[ff]);
      fa_l[ff] = *(const bf16x8*)(a_rd[ff] + lo_off_a);
      fb_h[ff] = *(const bf16x8*)(b_rd[ff]);
      fb_l[ff] = *(const bf16x8*)(b_rd[ff] + lo_off_b);
    }
#pragma unroll
    for (int i = 0; i < 4; ++i)
#pragma unroll
      for (int j = 0; j < 4; ++j) {
        acc[i][j] = __builtin_amdgcn_mfma_f32_16x16x32_bf16(fa_h[i], fb_h[j], acc[i][j], 0, 0, 0);
        acc[i][j] = __builtin_amdgcn_mfma_f32_16x16x32_bf16(fa_l[i], fb_h[j], acc[i][j], 0, 0, 0);
        acc[i][j] = __builtin_amdgcn_mfma_f32_16x16x32_bf16(fa_h[i], fb_l[j], acc[i][j], 0, 0, 0);
      }
    __syncthreads();
  }

  // Epilogue: bias + relu. C layout: col=lane&15, row=(lane>>4)*4+reg
#pragma unroll
  for (int fn = 0; fn < 4; ++fn) {
    const int n = n0 + wn * 64 + fn * 16 + (lane & 15);
    const float bias = b1[n];
#pragma unroll
    for (int fm = 0; fm < 4; ++fm) {
      const int mbase = m0 + wm * 64 + fm * 16 + (lane >> 4) * 4;
#pragma unroll
      for (int r = 0; r < 4; ++r) {
        float vv = acc[fm][fn][r] + bias;
        Hout[(size_t)(mbase + r) * H_DIM + n] = fmaxf(vv, 0.f);
      }
    }
  }
}

// ---------------------------------------------------------------------------
// K2 fused: logits = h @ W2^T + b2  (bf16x3 MFMA)  ->  top-2 + softmax
// weights + entropy, all in one block. M-tile=64, E=64, BK=32, 256 threads
// (4 waves, wave w owns rows [w*16, w*16+16) x all 64 experts).
// h is fp32 (split in-kernel); W2 pre-split hi/lo bf16.
// ---------------------------------------------------------------------------
#define F_BM 64
#define F_BK 32

__global__ __launch_bounds__(256) void gemm2_router_kernel(
    const float* __restrict__ h,
    const unsigned short* __restrict__ w2h,
    const unsigned short* __restrict__ w2l,
    const float* __restrict__ b2,
    float* __restrict__ out, float* __restrict__ accum) {
  __shared__ unsigned short Ah[F_BM * F_BK];   // 4 KB each
  __shared__ unsigned short Al[F_BM * F_BK];
  __shared__ unsigned short Bh[E_DIM * F_BK];
  __shared__ unsigned short Bl[E_DIM * F_BK];
  __shared__ float LG[F_BM][E_DIM + 1];        // +1 pad: kills 64-way col conflict

  const int t    = threadIdx.x;
  const int lane = t & 63;
  const int w    = t >> 6;
  const int m0   = blockIdx.x * F_BM;

  // A staging: 8 contiguous fp32 along k per thread, split to hi/lo bf16
  const int ar = t >> 2;          // row 0..63
  const int ac = (t & 3) * 8;     // col 0,8,16,24
  const float* hp = h + (size_t)(m0 + ar) * H_DIM + ac;
  unsigned short* ah_w = &Ah[ar * F_BK + ac];
  unsigned short* al_w = &Al[ar * F_BK + ac];

  // B staging via global_load_lds: element offset e = t*8 (wave-uniform base
  // + lane*16B). row = t>>2, col = (t&3)*8 in the [64][32] tile.
  const unsigned short* bh_g = w2h + (size_t)ar * H_DIM + ac;
  const unsigned short* bl_g = w2l + (size_t)ar * H_DIM + ac;
  unsigned short* bh_l = &Bh[t * 8];
  unsigned short* bl_l = &Bl[t * 8];

  // Fragment read addresses
  const int koff = (lane >> 4) * 8;
  const unsigned short* a_rd = &Ah[(w * 16 + (lane & 15)) * F_BK + koff];
  const unsigned short* b_rd[4];
#pragma unroll
  for (int f = 0; f < 4; ++f)
    b_rd[f] = &Bh[(f * 16 + (lane & 15)) * F_BK + koff];
  const int lo_off_a = (int)(Al - Ah);
  const int lo_off_b = (int)(Bl - Bh);

  f32x4 acc[4];
#pragma unroll
  for (int f = 0; f < 4; ++f) acc[f] = (f32x4)0.f;

  for (int k0 = 0; k0 < H_DIM; k0 += F_BK) {
    async_copy16(bh_g + k0, bh_l);
    async_copy16(bl_g + k0, bl_l);

    float4 v0 = *(const float4*)(hp + k0);
    float4 v1 = *(const float4*)(hp + k0 + 4);
    float f[8] = {v0.x, v0.y, v0.z, v0.w, v1.x, v1.y, v1.z, v1.w};
    ushort8 hv, lv;
#pragma unroll
    for (int j = 0; j < 8; ++j) {
      unsigned short hh = bf_rne(f[j]);
      float fh = __uint_as_float(((unsigned)hh) << 16);
      hv[j] = hh;
      lv[j] = bf_rne(f[j] - fh);
    }
    *(ushort8*)ah_w = hv;
    *(ushort8*)al_w = lv;

    __syncthreads();

    bf16x8 fa_h = *(const bf16x8*)(a_rd);
    bf16x8 fa_l = *(const bf16x8*)(a_rd + lo_off_a);
#pragma unroll
    for (int f = 0; f < 4; ++f) {
      bf16x8 fb_h = *(const bf16x8*)(b_rd[f]);
      bf16x8 fb_l = *(const bf16x8*)(b_rd[f] + lo_off_b);
      acc[f] = __builtin_amdgcn_mfma_f32_16x16x32_bf16(fa_h, fb_h, acc[f], 0, 0, 0);
      acc[f] = __builtin_amdgcn_mfma_f32_16x16x32_bf16(fa_l, fb_h, acc[f], 0, 0, 0);
      acc[f] = __builtin_amdgcn_mfma_f32_16x16x32_bf16(fa_h, fb_l, acc[f], 0, 0, 0);
    }
    __syncthreads();
  }

  // Epilogue: bias, stash logits tile in LDS.
  // C layout: col(expert)=lane&15, row=(lane>>4)*4+reg
#pragma unroll
  for (int f = 0; f < 4; ++f) {
    const int e = f * 16 + (lane & 15);
    const float bias = b2[e];
#pragma unroll
    for (int r = 0; r < 4; ++r) {
      const int ml = w * 16 + (lane >> 4) * 4 + r;
      LG[ml][e] = acc[f][r] + bias;
    }
  }
  __syncthreads();

  // Router: threads 0..63 each own one row.
  if (t < F_BM) {
    const int row = m0 + t;
    float l0 = LG[t][0]; int i0 = 0;
    float l1 = -INFINITY; int i1 = -1;
#pragma unroll
    for (int e = 1; e < E_DIM; ++e) {
      float v = LG[t][e];
      if (v > l0)      { l1 = l0; i1 = i0; l0 = v; i0 = e; }
      else if (v > l1) { l1 = v; i1 = e; }
    }

    const float eT = expf((l1 - l0) / TEMP);
    const float w0 = 1.f / (1.f + eT);
    const float w1 = eT / (1.f + eT);

    float Z = 0.f;
#pragma unroll
    for (int e = 0; e < E_DIM; ++e) Z += expf(LG[t][e] - l0);
    const float invZ = 1.f / Z;
    float ent = 0.f;
#pragma unroll
    for (int e = 0; e < E_DIM; ++e) {
      float p = expf(LG[t][e] - l0) * invZ;
      ent -= p * logf(p + 1e-10f);
    }

    out[(size_t)row * 2 + 0] = w0;
    out[(size_t)row * 2 + 1] = w1;
    out[(size_t)B_ROWS * 2 + (size_t)row * 2 + 0] = (float)i0;
    out[(size_t)B_ROWS * 2 + (size_t)row * 2 + 1] = (float)i1;

    // wave-0 shuffle reduction of entropy (threads 0..63 are one wave)
#pragma unroll
    for (int off = 32; off > 0; off >>= 1) ent += __shfl_down(ent, off);
    if (t == 0) atomicAdd(accum, ent);
  }
}

__global__ void zero_kernel(float* p) { p[0] = 0.f; }

__global__ void finalize_kernel(const float* __restrict__ accum,
                                float* __restrict__ out) {
  out[(size_t)B_ROWS * 4] = accum[0] / ((float)B_ROWS * logf((float)E_DIM));
}

// ---------------------------------------------------------------------------
extern "C" void kernel_launch(void* const* d_in, const int* in_sizes, int n_in,
                              void* d_out, int out_size, void* d_ws,
                              size_t ws_size, hipStream_t stream) {
  const float* x  = (const float*)d_in[0];
  const float* W1 = (const float*)d_in[1];
  const float* b1 = (const float*)d_in[2];
  const float* W2 = (const float*)d_in[3];
  const float* b2 = (const float*)d_in[4];
  float* out = (float*)d_out;

  // ws layout: w1h/w1l (16.8 MB each), w2h/w2l (0.26 MB each), h (134 MB), accum
  unsigned short* w1h = (unsigned short*)d_ws;
  unsigned short* w1l = w1h + (size_t)H_DIM * D_DIM;
  unsigned short* w2h = w1l + (size_t)H_DIM * D_DIM;
  unsigned short* w2l = w2h + (size_t)E_DIM * H_DIM;
  float* h     = (float*)(w2l + (size_t)E_DIM * H_DIM);
  float* accum = h + (size_t)B_ROWS * H_DIM;

  zero_kernel<<<1, 1, 0, stream>>>(accum);

  split_kernel<<<(H_DIM * D_DIM) / (256 * 8), 256, 0, stream>>>(W1, w1h, w1l);
  split_kernel<<<(E_DIM * H_DIM) / (256 * 8), 256, 0, stream>>>(W2, w2h, w2l);

  dim3 g1(H_DIM / BN, B_ROWS / BM);  // (16, 128)
  gemm1_mfma_kernel<<<g1, 256, 0, stream>>>(x, w1h, w1l, b1, h);

  gemm2_router_kernel<<<B_ROWS / F_BM, 256, 0, stream>>>(h, w2h, w2l, b2, out, accum);

  finalize_kernel<<<1, 1, 0, stream>>>(accum, out);
}